// Round 17
// baseline (118.326 us; speedup 1.0000x reference)
//
#include <hip/hip_runtime.h>

#define N_NETS  131072
#define N_PINS  (N_NETS * 4)
#define N_NODES 55000
#define NBBLK   256                // bbox blocks (512 threads, RPB records each)
#define RPB     516                // 256*516 >= 131072+96
#define NPARTS  2
#define CELLCAP 128                // per-(slab,block); slab0 mean ~64, +8 sigma

// Inline 32B scatter entries: A = {c0|c1<<16|rr<<29, c2|c3<<16, ah, av},
// B = pys (float4). Slab = row>>3 (contiguous 8-row slabs; slight skew OK).
__device__ uint4 g_ent[64 * NBBLK * CELLCAP * 2];
__device__ unsigned short g_cellcnt[64 * NBBLK];     // [slab][block]
// Transposed interface: g_part[p][map][cy][x] — dense 2KB runs for k_finish.
__device__ float g_part[NPARTS * 2 * 512 * 512];
__device__ int      g_cnt2[2];
__device__ unsigned g_tick;                          // epoch: &63

__global__ __launch_bounds__(512) void k_bbox(
    const float* __restrict__ pos, const float* __restrict__ pin_pos,
    const float* __restrict__ nsx, const float* __restrict__ nsy,
    const float* __restrict__ nw,  const int* __restrict__ fnp,
    const int* __restrict__ mid, int nm)
{
    __shared__ int s_cnt[64];
    int tid = threadIdx.x;
    int b = blockIdx.x;
    if (b == 0 && tid == 0) { g_cnt2[0] = 0; g_cnt2[1] = 0; g_tick = 0; }
    if (tid < 64) s_cnt[tid] = 0;
    __syncthreads();

    int tEnd = min((b + 1) * RPB, N_NETS + nm);
    for (int t = b * RPB + tid; t < tEnd; t += 512) {
        float xmin, xmax, ymin, ymax, wh, wv;
        if (t < N_NETS) {
            int4 p = ((const int4*)fnp)[t];
            float x0 = pin_pos[p.x], x1 = pin_pos[p.y], x2 = pin_pos[p.z], x3 = pin_pos[p.w];
            float y0 = pin_pos[N_PINS + p.x], y1 = pin_pos[N_PINS + p.y];
            float y2 = pin_pos[N_PINS + p.z], y3 = pin_pos[N_PINS + p.w];
            xmin = fminf(fminf(x0, x1), fminf(x2, x3));
            xmax = fmaxf(fmaxf(x0, x1), fmaxf(x2, x3));
            ymin = fminf(fminf(y0, y1), fminf(y2, y3));
            ymax = fmaxf(fmaxf(y0, y1), fmaxf(y2, y3));
            float w = nw[t];
            wh = w / (ymax - ymin);
            wv = w / (xmax - xmin);
        } else {
            int idx = mid[t - N_NETS];
            xmin = pos[idx]; ymin = pos[N_NODES + idx];
            float sx = nsx[idx], sy = nsy[idx];
            xmax = xmin + sx; ymax = ymin + sy;
            wh = wv = 10.0f / (sx * sy);
        }
        const float B = 1.0f / 512.0f;
        int xl = min(max((int)(xmin * 512.0f), 0), 511);
        int xh = min(max((int)(xmax * 512.0f), 0), 511);
        int yl = min(max((int)(ymin * 512.0f), 0), 511);
        int yh = min(max((int)(ymax * 512.0f), 0), 511);
        unsigned w0c = (unsigned)yl | ((unsigned)(yl + 1) << 16);
        unsigned w1c = (unsigned)yh | ((unsigned)(yh + 1) << 16);
        uint4 Bq = make_uint4(__float_as_uint((yl + 1) * B - ymin),
                              __float_as_uint(ymin - yl * B),
                              __float_as_uint(ymax - (yh + 1) * B),
                              __float_as_uint(yh * B - ymax));

        auto put = [&](int row, float px) {
            int s = row >> 3;                       // contiguous slab
            int slot = atomicAdd(&s_cnt[s], 1);
            if (slot < CELLCAP) {
                uint4 A;
                A.x = w0c | ((unsigned)(row & 7) << 29);
                A.y = w1c;
                A.z = __float_as_uint(px * wh);
                A.w = __float_as_uint(px * wv);
                unsigned base = ((unsigned)(s * NBBLK + b) * CELLCAP + (unsigned)slot) * 2u;
                g_ent[base]     = A;
                g_ent[base + 1] = Bq;
            }
        };
        put(xl, (xl + 1) * B - xmin);
        if (xl + 1 < 512) put(xl + 1, xmin - xl * B);
        put(xh, xmax - (xh + 1) * B);
        if (xh + 1 < 512) put(xh + 1, xh * B - xmax);
    }
    __syncthreads();
    if (tid < 64) g_cellcnt[tid * NBBLK + b] = (unsigned short)min(s_cnt[tid], CELLCAP);
}

// 128 blocks = 64 slabs x 2 parts. Slab s = rows [8s, 8s+8). After LDS
// y-scan, transpose-write: each thread emits one col's 8 x-floats (32B dense).
__global__ __launch_bounds__(1024) void k_deposit() {
    __shared__ float tile[8706];           // 8 rows x 1024 interleaved + dummy @8192
    __shared__ int s_pref[128];
    __shared__ int s_wt[2];
    __shared__ int s_total;
    int tid = threadIdx.x;
    int s = blockIdx.x >> 1, p = blockIdx.x & 1;
#pragma unroll
    for (int k = tid; k < 8706; k += 1024) tile[k] = 0.0f;

    int lob = p * 128;                     // this part's 128 bbox-blocks
    if (tid < 128) {
        int c = (int)g_cellcnt[s * NBBLK + lob + tid];
        int v = c;
#pragma unroll
        for (int off = 1; off < 64; off <<= 1) {
            int tv = __shfl_up(v, off);
            if ((tid & 63) >= off) v += tv;
        }
        s_pref[tid] = v - c;
        if ((tid & 63) == 63) s_wt[tid >> 6] = v;
    }
    __syncthreads();
    if (tid >= 64 && tid < 128) s_pref[tid] += s_wt[0];
    if (tid == 0) s_total = s_wt[0] + s_wt[1];
    __syncthreads();

    int total = s_total;
    for (int k = tid; k < total; k += 1024) {
        int loJ = 0, hiJ = 127;            // largest j with s_pref[j] <= k
#pragma unroll
        for (int st = 0; st < 7; ++st) {
            int mid_ = (loJ + hiJ + 1) >> 1;
            if (s_pref[mid_] <= k) loJ = mid_; else hiJ = mid_ - 1;
        }
        unsigned gidx = ((unsigned)(s * NBBLK + lob + loJ) * CELLCAP
                         + (unsigned)(k - s_pref[loJ])) * 2u;
        uint4 A  = g_ent[gidx];
        uint4 Bq = g_ent[gidx + 1];
        int rr = (int)(A.x >> 29);
        unsigned c0 = A.x & 0xFFFFu, c1 = (A.x >> 16) & 0x1FFFu;
        unsigned c2 = A.y & 0xFFFFu, c3 = A.y >> 16;
        float ah = __uint_as_float(A.z), av = __uint_as_float(A.w);
        float p0 = __uint_as_float(Bq.x), p1 = __uint_as_float(Bq.y);
        float p2 = __uint_as_float(Bq.z), p3 = __uint_as_float(Bq.w);
        int base = rr * 1024;
        int i0 = (c0 < 512u) ? base + 2 * (int)c0 : 8192;
        int i1 = (c1 < 512u) ? base + 2 * (int)c1 : 8192;
        int i2 = (c2 < 512u) ? base + 2 * (int)c2 : 8192;
        int i3 = (c3 < 512u) ? base + 2 * (int)c3 : 8192;
        unsafeAtomicAdd(&tile[i0],     ah * p0);
        unsafeAtomicAdd(&tile[i0 + 1], av * p0);
        unsafeAtomicAdd(&tile[i1],     ah * p1);
        unsafeAtomicAdd(&tile[i1 + 1], av * p1);
        unsafeAtomicAdd(&tile[i2],     ah * p2);
        unsafeAtomicAdd(&tile[i2 + 1], av * p2);
        unsafeAtomicAdd(&tile[i3],     ah * p3);
        unsafeAtomicAdd(&tile[i3 + 1], av * p3);
    }
    __syncthreads();

    // y-scan: 8 waves, wave r scans tile row r as float2 (H,V), carry chain
    int wid = tid >> 6, lane = tid & 63;
    if (wid < 8) {
        float2* rowp = (float2*)&tile[wid * 1024];
        float cx = 0.0f, cy = 0.0f;
        for (int ch = 0; ch < 8; ++ch) {
            float2 v = rowp[ch * 64 + lane];
#pragma unroll
            for (int off = 1; off < 64; off <<= 1) {
                float tx = __shfl_up(v.x, off);
                float ty = __shfl_up(v.y, off);
                if (lane >= off) { v.x += tx; v.y += ty; }
            }
            v.x += cx; v.y += cy;
            rowp[ch * 64 + lane] = v;
            cx = __shfl(v.x, 63); cy = __shfl(v.y, 63);
        }
    }
    __syncthreads();

    // Transpose-write: thread c -> g_part[p][map][cy][8s..8s+8) (32B dense)
    {
        int c = tid;                       // tile col = 2*cy + map
        int mp = c & 1, cy = c >> 1;
        float t0 = tile[c],            t1 = tile[c + 1024];
        float t2 = tile[c + 2048],     t3 = tile[c + 3072];
        float t4 = tile[c + 4096],     t5 = tile[c + 5120];
        float t6 = tile[c + 6144],     t7 = tile[c + 7168];
        float* dst = &g_part[(((p * 2 + mp) * 512 + cy) << 9) + 8 * s];
        *(float4*)dst       = make_float4(t0, t1, t2, t3);
        *(float4*)(dst + 4) = make_float4(t4, t5, t6, t7);
    }
}

// 64 blocks, block b owns output cols cy in [8b, 8b+8). Dense part-merge +
// y-blur fused into the load (6 coalesced loads per float); chunked x-scan;
// x-blur fused into final read; map/counts; ticket.
__global__ __launch_bounds__(1024) void k_finish(float* __restrict__ out) {
    __shared__ float sB[16 * 512];         // [map*8+t][x], y-blurred scaled
    __shared__ int scnt[2];
    int tid = threadIdx.x;
    int b = blockIdx.x;
    int lane = tid & 63;
    const float kw  = expf(-0.5f / 1024.0f);
    const float k1n = 1.0f / (1.0f + 2.0f * kw);
    const float k0n = kw * k1n;
    const float scale = 262144.0f / 50000.0f;

    // load + merge + y-blur: 16 rows x 512 x, consecutive tid -> consecutive x
#pragma unroll
    for (int k = 0; k < 8; ++k) {
        int i = tid + k * 1024;            // [0, 8192)
        int x = i & 511, r = i >> 9;       // r in [0,16)
        int mp = r >> 3, t = r & 7;
        int cy = 8 * b + t;
        int cym = (cy == 0) ? 1 : cy - 1;
        int cyp = (cy == 511) ? 510 : cy + 1;
        float v = 0.0f;
#pragma unroll
        for (int p = 0; p < NPARTS; ++p) {
            const float* g = &g_part[((p * 2 + mp) * 512) << 9];
            v += k0n * (g[(cym << 9) + x] + g[(cyp << 9) + x])
               + k1n * g[(cy << 9) + x];
        }
        sB[r * 512 + x] = v * scale;
    }
    __syncthreads();

    // x-scan: wave w owns sB row w; 8 chunks of 64, lane-stride-1
    {
        int w = tid >> 6;
        float carry = 0.0f;
        for (int ch = 0; ch < 8; ++ch) {
            float v = sB[w * 512 + ch * 64 + lane];
#pragma unroll
            for (int off = 1; off < 64; off <<= 1) {
                float tv = __shfl_up(v, off);
                if (lane >= off) v += tv;
            }
            v += carry;
            sB[w * 512 + ch * 64 + lane] = v;
            carry = __shfl(v, 63);
        }
    }
    __syncthreads();

    // final: x-blur on the fly (reflect), map, counts
    int x = tid >> 1, qh = (tid & 1) * 4;
    int xm = (x == 0) ? 1 : x - 1;
    int xp = (x == 511) ? 510 : x + 1;
    float4 o;
    int ch_ = 0, cv_ = 0;
#pragma unroll
    for (int k = 0; k < 4; ++k) {
        int tt = qh + k;
        const float* rH = &sB[tt * 512];
        const float* rV = &sB[(8 + tt) * 512];
        float hv = k0n * (rH[xm] + rH[xp]) + k1n * rH[x];
        float vv = k0n * (rV[xm] + rV[xp]) + k1n * rV[x];
        ((float*)&o)[k] = fmaxf(fabsf(hv), fabsf(vv));
        ch_ += (hv > 1.0f); cv_ += (vv > 1.0f);
    }
    *(float4*)&out[x * 512 + 8 * b + qh] = o;
#pragma unroll
    for (int off = 32; off > 0; off >>= 1) {
        ch_ += __shfl_down(ch_, off);
        cv_ += __shfl_down(cv_, off);
    }
    if (tid < 2) scnt[tid] = 0;
    __syncthreads();
    if (lane == 0) { atomicAdd(&scnt[0], ch_); atomicAdd(&scnt[1], cv_); }
    __syncthreads();
    if (tid == 0) {
        atomicAdd(&g_cnt2[0], scnt[0]);
        atomicAdd(&g_cnt2[1], scnt[1]);
        __threadfence();
        unsigned old = atomicAdd(&g_tick, 1u);
        if ((old & 63u) == 63u) {
            __threadfence();
            int h = atomicAdd(&g_cnt2[0], 0);
            int v = atomicAdd(&g_cnt2[1], 0);
            out[262144] = (float)((h > v) ? h : v);   // max_overflow
            out[262145] = (float)(h + v);             // total_overflow
        }
    }
}

extern "C" void kernel_launch(void* const* d_in, const int* in_sizes, int n_in,
                              void* d_out, int out_size, void* d_ws, size_t ws_size,
                              hipStream_t stream) {
    const float* pos     = (const float*)d_in[0];
    const float* pin_pos = (const float*)d_in[1];
    const float* nsx     = (const float*)d_in[2];
    const float* nsy     = (const float*)d_in[3];
    const float* nw      = (const float*)d_in[4];
    const int*   fnp     = (const int*)d_in[5];
    const int*   mid     = (const int*)d_in[6];
    int nm = in_sizes[6];
    float* out = (float*)d_out;

    hipLaunchKernelGGL(k_bbox,    dim3(NBBLK), dim3(512), 0, stream,
                       pos, pin_pos, nsx, nsy, nw, fnp, mid, nm);
    hipLaunchKernelGGL(k_deposit, dim3(128), dim3(1024), 0, stream);
    hipLaunchKernelGGL(k_finish,  dim3(64), dim3(1024), 0, stream, out);
}

// Round 18
// 64.963 us; speedup vs baseline: 1.8214x; 1.8214x over previous
//
#include <hip/hip_runtime.h>

#define N_NETS  131072
#define N_PINS  (N_NETS * 4)
#define N_NODES 55000
#define NBBLK   256                // bbox blocks (512 threads, RPB records each)
#define RPB     516                // 256*516 >= 131072+96
#define NPARTS  4
#define CELLCAP 96                 // per-(slab,block); mean ~34, +10 sigma

// Inline 32B scatter entries: A = {c0|c1<<16|rr<<29, c2|c3<<16, ah, av},
// B = pys (float4). Row-permuted slabs: slab(r) = r & 63 (uniform load).
__device__ uint4 g_ent[64 * NBBLK * CELLCAP * 2];
__device__ unsigned short g_cellcnt[64 * NBBLK];     // [slab][block]
__device__ float g_part[NPARTS * 512 * 1024];        // [p][x][2*y+map]
__device__ int      g_cnt2[2];
__device__ unsigned g_tick;                          // epoch: &63

__global__ __launch_bounds__(512) void k_bbox(
    const float* __restrict__ pos, const float* __restrict__ pin_pos,
    const float* __restrict__ nsx, const float* __restrict__ nsy,
    const float* __restrict__ nw,  const int* __restrict__ fnp,
    const int* __restrict__ mid, int nm)
{
    __shared__ int s_cnt[64];
    int tid = threadIdx.x;
    int b = blockIdx.x;
    if (b == 0 && tid == 0) { g_cnt2[0] = 0; g_cnt2[1] = 0; g_tick = 0; }
    if (tid < 64) s_cnt[tid] = 0;
    __syncthreads();

    int tEnd = min((b + 1) * RPB, N_NETS + nm);
    for (int t = b * RPB + tid; t < tEnd; t += 512) {
        float xmin, xmax, ymin, ymax, wh, wv;
        if (t < N_NETS) {
            int4 p = ((const int4*)fnp)[t];
            float x0 = pin_pos[p.x], x1 = pin_pos[p.y], x2 = pin_pos[p.z], x3 = pin_pos[p.w];
            float y0 = pin_pos[N_PINS + p.x], y1 = pin_pos[N_PINS + p.y];
            float y2 = pin_pos[N_PINS + p.z], y3 = pin_pos[N_PINS + p.w];
            xmin = fminf(fminf(x0, x1), fminf(x2, x3));
            xmax = fmaxf(fmaxf(x0, x1), fmaxf(x2, x3));
            ymin = fminf(fminf(y0, y1), fminf(y2, y3));
            ymax = fmaxf(fmaxf(y0, y1), fmaxf(y2, y3));
            float w = nw[t];
            wh = w / (ymax - ymin);
            wv = w / (xmax - xmin);
        } else {
            int idx = mid[t - N_NETS];
            xmin = pos[idx]; ymin = pos[N_NODES + idx];
            float sx = nsx[idx], sy = nsy[idx];
            xmax = xmin + sx; ymax = ymin + sy;
            wh = wv = 10.0f / (sx * sy);
        }
        const float B = 1.0f / 512.0f;
        int xl = min(max((int)(xmin * 512.0f), 0), 511);
        int xh = min(max((int)(xmax * 512.0f), 0), 511);
        int yl = min(max((int)(ymin * 512.0f), 0), 511);
        int yh = min(max((int)(ymax * 512.0f), 0), 511);
        unsigned w0c = (unsigned)yl | ((unsigned)(yl + 1) << 16);
        unsigned w1c = (unsigned)yh | ((unsigned)(yh + 1) << 16);
        uint4 Bq = make_uint4(__float_as_uint((yl + 1) * B - ymin),
                              __float_as_uint(ymin - yl * B),
                              __float_as_uint(ymax - (yh + 1) * B),
                              __float_as_uint(yh * B - ymax));

        auto put = [&](int row, float px) {
            int s = row & 63;                       // row-permuted slab
            int slot = atomicAdd(&s_cnt[s], 1);
            if (slot < CELLCAP) {
                uint4 A;
                A.x = w0c | ((unsigned)(row >> 6) << 29);
                A.y = w1c;
                A.z = __float_as_uint(px * wh);
                A.w = __float_as_uint(px * wv);
                unsigned base = ((unsigned)(s * NBBLK + b) * CELLCAP + (unsigned)slot) * 2u;
                g_ent[base]     = A;
                g_ent[base + 1] = Bq;
            }
        };
        put(xl, (xl + 1) * B - xmin);
        if (xl + 1 < 512) put(xl + 1, xmin - xl * B);
        put(xh, xmax - (xh + 1) * B);
        if (xh + 1 < 512) put(xh + 1, xh * B - xmax);
    }
    __syncthreads();
    if (tid < 64) g_cellcnt[tid * NBBLK + b] = (unsigned short)min(s_cnt[tid], CELLCAP);
}

// 256 blocks = 64 slabs x 4 parts (slab-major). Wave w owns 4 cells of its
// part: register prefix + 2-compare lookup per entry (NO per-entry LDS search).
__global__ __launch_bounds__(1024) void k_deposit() {
    __shared__ float tile[8706];           // 8 rows x 1024 interleaved + dummy @8192
    int tid = threadIdx.x;
    int s = blockIdx.x >> 2, p = blockIdx.x & 3;
#pragma unroll
    for (int k = tid; k < 8706; k += 1024) tile[k] = 0.0f;
    __syncthreads();

    int wid = tid >> 6, lane = tid & 63;
    int cb = p * 64 + wid * 4;             // this wave's 4 cells (bbox-blocks)
    int n0 = (int)g_cellcnt[s * NBBLK + cb + 0];
    int n1 = (int)g_cellcnt[s * NBBLK + cb + 1];
    int n2 = (int)g_cellcnt[s * NBBLK + cb + 2];
    int n3 = (int)g_cellcnt[s * NBBLK + cb + 3];
    int pre1 = n0, pre2 = n0 + n1, pre3 = n0 + n1 + n2;
    int tot = pre3 + n3;
    unsigned cbase = (unsigned)(s * NBBLK + cb) * CELLCAP;

    for (int k = lane; k < tot; k += 64) {
        int j, idx;
        if (k < pre2) { j = (k >= pre1); idx = k - (j ? pre1 : 0); }
        else          { j = 2 + (k >= pre3); idx = k - ((j == 3) ? pre3 : pre2); }
        unsigned gidx = (cbase + (unsigned)(j * CELLCAP + idx)) * 2u;
        uint4 A  = g_ent[gidx];
        uint4 Bq = g_ent[gidx + 1];
        int rr = (int)(A.x >> 29);
        unsigned c0 = A.x & 0xFFFFu, c1 = (A.x >> 16) & 0x1FFFu;
        unsigned c2 = A.y & 0xFFFFu, c3 = A.y >> 16;
        float ah = __uint_as_float(A.z), av = __uint_as_float(A.w);
        float p0 = __uint_as_float(Bq.x), p1 = __uint_as_float(Bq.y);
        float p2 = __uint_as_float(Bq.z), p3 = __uint_as_float(Bq.w);
        int base = rr * 1024;
        int i0 = (c0 < 512u) ? base + 2 * (int)c0 : 8192;
        int i1 = (c1 < 512u) ? base + 2 * (int)c1 : 8192;
        int i2 = (c2 < 512u) ? base + 2 * (int)c2 : 8192;
        int i3 = (c3 < 512u) ? base + 2 * (int)c3 : 8192;
        unsafeAtomicAdd(&tile[i0],     ah * p0);
        unsafeAtomicAdd(&tile[i0 + 1], av * p0);
        unsafeAtomicAdd(&tile[i1],     ah * p1);
        unsafeAtomicAdd(&tile[i1 + 1], av * p1);
        unsafeAtomicAdd(&tile[i2],     ah * p2);
        unsafeAtomicAdd(&tile[i2 + 1], av * p2);
        unsafeAtomicAdd(&tile[i3],     ah * p3);
        unsafeAtomicAdd(&tile[i3 + 1], av * p3);
    }
    __syncthreads();

    // y-scan: 8 waves, wave r scans tile row r as float2 (H,V), carry chain
    if (wid < 8) {
        float2* rowp = (float2*)&tile[wid * 1024];
        float cx = 0.0f, cy = 0.0f;
        for (int ch = 0; ch < 8; ++ch) {
            float2 v = rowp[ch * 64 + lane];
#pragma unroll
            for (int off = 1; off < 64; off <<= 1) {
                float tx = __shfl_up(v.x, off);
                float ty = __shfl_up(v.y, off);
                if (lane >= off) { v.x += tx; v.y += ty; }
            }
            v.x += cx; v.y += cy;
            rowp[ch * 64 + lane] = v;
            cx = __shfl(v.x, 63); cy = __shfl(v.y, 63);
        }
    }
    __syncthreads();
    // Un-permute on write: tile row rr -> global row (rr<<6)|s
    int dstp = p * 524288 + (s << 10);
#pragma unroll
    for (int k = 0; k < 8; ++k) {
        int idx = tid + k * 1024;
        int rr = idx >> 10, cc = idx & 1023;
        g_part[dstp + (rr << 16) + cc] = tile[idx];
    }
}

// 64 blocks, block b owns output cols y in [8b, 8b+8). Batched merge +
// y-blur -> sB; chunked conflict-free x-scan; x-blur fused into final read.
__global__ __launch_bounds__(1024) void k_finish(float* __restrict__ out) {
    __shared__ float sB[16 * 512];
    __shared__ int scnt[2];
    int tid = threadIdx.x;
    int b = blockIdx.x;
    int lane = tid & 63;
    int c20 = tid & 31;
    int xg = tid >> 5;
    int jj = (c20 < 10) ? c20 : c20 - 10;
    int cy = 8 * b - 1 + jj;
    if (cy < 0) cy = 1;
    if (cy > 511) cy = 510;
    int map = (c20 < 10) ? 0 : 1;
    int gcol = 2 * cy + map;
    const float kw  = expf(-0.5f / 1024.0f);
    const float k1n = 1.0f / (1.0f + 2.0f * kw);
    const float k0n = kw * k1n;
    const float scale = 262144.0f / 50000.0f;
    bool active = c20 < 20;
    int t8  = (c20 < 10) ? c20 - 1 : c20 - 11;

    for (int xo4 = 0; xo4 < 4; ++xo4) {
        float acc[4];
#pragma unroll
        for (int j = 0; j < 4; ++j) {
            int x = (xo4 * 4 + j) * 32 + xg;
            float v = 0.0f;
            if (active) {
                int base = x * 1024 + gcol;
#pragma unroll
                for (int p = 0; p < NPARTS; ++p) v += g_part[p * 524288 + base];
            }
            acc[j] = v;
        }
#pragma unroll
        for (int j = 0; j < 4; ++j) {
            int x = (xo4 * 4 + j) * 32 + xg;
            float vm = __shfl(acc[j], lane - 1);
            float vp = __shfl(acc[j], lane + 1);
            float yb = (k0n * (vm + vp) + k1n * acc[j]) * scale;
            if (t8 >= 0 && t8 < 8) sB[(map * 8 + t8) * 512 + x] = yb;
        }
    }
    __syncthreads();

    {
        int w = tid >> 6;
        float carry = 0.0f;
        for (int ch = 0; ch < 8; ++ch) {
            float v = sB[w * 512 + ch * 64 + lane];
#pragma unroll
            for (int off = 1; off < 64; off <<= 1) {
                float tv = __shfl_up(v, off);
                if (lane >= off) v += tv;
            }
            v += carry;
            sB[w * 512 + ch * 64 + lane] = v;
            carry = __shfl(v, 63);
        }
    }
    __syncthreads();

    int x = tid >> 1, qh = (tid & 1) * 4;
    int xm = (x == 0) ? 1 : x - 1;
    int xp = (x == 511) ? 510 : x + 1;
    float4 o;
    int ch_ = 0, cv_ = 0;
#pragma unroll
    for (int k = 0; k < 4; ++k) {
        int tt = qh + k;
        const float* rH = &sB[tt * 512];
        const float* rV = &sB[(8 + tt) * 512];
        float hv = k0n * (rH[xm] + rH[xp]) + k1n * rH[x];
        float vv = k0n * (rV[xm] + rV[xp]) + k1n * rV[x];
        ((float*)&o)[k] = fmaxf(fabsf(hv), fabsf(vv));
        ch_ += (hv > 1.0f); cv_ += (vv > 1.0f);
    }
    *(float4*)&out[x * 512 + 8 * b + qh] = o;
#pragma unroll
    for (int off = 32; off > 0; off >>= 1) {
        ch_ += __shfl_down(ch_, off);
        cv_ += __shfl_down(cv_, off);
    }
    if (tid < 2) scnt[tid] = 0;
    __syncthreads();
    if (lane == 0) { atomicAdd(&scnt[0], ch_); atomicAdd(&scnt[1], cv_); }
    __syncthreads();
    if (tid == 0) {
        atomicAdd(&g_cnt2[0], scnt[0]);
        atomicAdd(&g_cnt2[1], scnt[1]);
        __threadfence();
        unsigned old = atomicAdd(&g_tick, 1u);
        if ((old & 63u) == 63u) {
            __threadfence();
            int h = atomicAdd(&g_cnt2[0], 0);
            int v = atomicAdd(&g_cnt2[1], 0);
            out[262144] = (float)((h > v) ? h : v);   // max_overflow
            out[262145] = (float)(h + v);             // total_overflow
        }
    }
}

extern "C" void kernel_launch(void* const* d_in, const int* in_sizes, int n_in,
                              void* d_out, int out_size, void* d_ws, size_t ws_size,
                              hipStream_t stream) {
    const float* pos     = (const float*)d_in[0];
    const float* pin_pos = (const float*)d_in[1];
    const float* nsx     = (const float*)d_in[2];
    const float* nsy     = (const float*)d_in[3];
    const float* nw      = (const float*)d_in[4];
    const int*   fnp     = (const int*)d_in[5];
    const int*   mid     = (const int*)d_in[6];
    int nm = in_sizes[6];
    float* out = (float*)d_out;

    hipLaunchKernelGGL(k_bbox,    dim3(NBBLK), dim3(512), 0, stream,
                       pos, pin_pos, nsx, nsy, nw, fnp, mid, nm);
    hipLaunchKernelGGL(k_deposit, dim3(256), dim3(1024), 0, stream);
    hipLaunchKernelGGL(k_finish,  dim3(64), dim3(1024), 0, stream, out);
}